// Round 3
// baseline (1091.535 us; speedup 1.0000x reference)
//
#include <hip/hip_runtime.h>
#include <cstdint>
#include <cstddef>

#define D   1024
#define DC  128      // d-chunk per block
#define TG  16       // max tokens processed per pass in dep kernel

__device__ __forceinline__ void fma4(float4& a, float s, const float4& w) {
    a.x = fmaf(s, w.x, a.x);
    a.y = fmaf(s, w.y, a.y);
    a.z = fmaf(s, w.z, a.z);
    a.w = fmaf(s, w.w, a.w);
}

// ---------------------------------------------------------------------------
// Kernel A: build counts[N][R] (float) and per-type token lists from edges.
// ---------------------------------------------------------------------------
__global__ void build_lists(const int* __restrict__ etok,
                            const int* __restrict__ etyp,
                            float* __restrict__ counts,
                            int* __restrict__ tcnt,
                            int* __restrict__ tlist,
                            int E, int R) {
    int i = blockIdx.x * blockDim.x + threadIdx.x;
    if (i < E) {
        int n = etok[i];
        int r = etyp[i];
        atomicAdd(&counts[(size_t)n * R + r], 1.0f);
        int idx = atomicAdd(&tcnt[r], 1);
        tlist[(size_t)r * E + idx] = n;
    }
}

// ---------------------------------------------------------------------------
// Kernel B: self term. block = (token n, d-chunk c). acc[n,e] += sum_d x*W_pos
// 256 threads, each owns 4 consecutive e (float4). Streams 512 KB of W_pos.
// ---------------------------------------------------------------------------
__global__ void __launch_bounds__(256)
self_kernel(const float* __restrict__ x,
            const float* __restrict__ Wpos,
            float* __restrict__ acc) {
    const int n  = blockIdx.x;
    const int d0 = blockIdx.y * DC;
    const int tid = threadIdx.x;

    __shared__ float xs[DC];
    if (tid < DC) xs[tid] = x[(size_t)n * D + d0 + tid];
    __syncthreads();

    const int e = tid * 4;
    const float* W = Wpos + ((size_t)n * D + d0) * D + e;

    float4 a = {0.f, 0.f, 0.f, 0.f};
    #pragma unroll 4
    for (int dd = 0; dd < DC; dd += 4) {
        const float4 xv = *(const float4*)&xs[dd];
        const float* Wd = W + (size_t)dd * D;
        float4 w0 = *(const float4*)(Wd);
        float4 w1 = *(const float4*)(Wd + D);
        float4 w2 = *(const float4*)(Wd + 2 * D);
        float4 w3 = *(const float4*)(Wd + 3 * D);
        fma4(a, xv.x, w0);
        fma4(a, xv.y, w1);
        fma4(a, xv.z, w2);
        fma4(a, xv.w, w3);
    }

    float* o = acc + (size_t)n * D + e;
    atomicAdd(o + 0, a.x);
    atomicAdd(o + 1, a.y);
    atomicAdd(o + 2, a.z);
    atomicAdd(o + 3, a.w);
}

// ---------------------------------------------------------------------------
// Kernel C: dep term, grouped by type. block = (type r, d-chunk c).
// Streams W_dep[r] chunk once; FMAs against up to TG token x-rows staged in
// LDS (zero-padded so the inner loop is branch-free). atomicAdd per token.
// ---------------------------------------------------------------------------
__global__ void __launch_bounds__(256)
dep_kernel(const float* __restrict__ x,
           const float* __restrict__ Wdep,
           const int* __restrict__ tcnt,
           const int* __restrict__ tlist,
           float* __restrict__ acc,
           int E) {
    const int r  = blockIdx.x;
    const int d0 = blockIdx.y * DC;
    const int cnt = tcnt[r];
    if (cnt == 0) return;

    const int tid = threadIdx.x;
    const int e = tid * 4;

    __shared__ float xs[DC][TG];   // [dd][i], uniform-address broadcast reads
    __shared__ int   toks[TG];

    const float* W = Wdep + ((size_t)r * D + d0) * D + e;

    for (int base = 0; base < cnt; base += TG) {
        const int m = min(TG, cnt - base);

        __syncthreads();   // previous pass done reading xs/toks
        if (tid < TG) {
            toks[tid] = (tid < m) ? tlist[(size_t)r * E + base + tid] : -1;
        }
        for (int k = tid; k < DC * TG; k += 256) {
            const int dd = k >> 4;       // k / TG
            const int i  = k & (TG - 1); // k % TG
            float v = 0.f;
            if (i < m) {
                const int t = tlist[(size_t)r * E + base + i];
                v = x[(size_t)t * D + d0 + dd];
            }
            xs[dd][i] = v;
        }
        __syncthreads();

        float4 a[TG];
        #pragma unroll
        for (int i = 0; i < TG; ++i) a[i] = make_float4(0.f, 0.f, 0.f, 0.f);

        for (int dd = 0; dd < DC; ++dd) {
            const float4 w = *(const float4*)(W + (size_t)dd * D);
            #pragma unroll
            for (int i4 = 0; i4 < TG / 4; ++i4) {
                const float4 xv = *(const float4*)&xs[dd][i4 * 4];
                fma4(a[i4 * 4 + 0], xv.x, w);
                fma4(a[i4 * 4 + 1], xv.y, w);
                fma4(a[i4 * 4 + 2], xv.z, w);
                fma4(a[i4 * 4 + 3], xv.w, w);
            }
        }

        #pragma unroll
        for (int i = 0; i < TG; ++i) {
            if (i < m) {
                const int t = toks[i];
                float* o = acc + (size_t)t * D + e;
                atomicAdd(o + 0, a[i].x);
                atomicAdd(o + 1, a[i].y);
                atomicAdd(o + 2, a[i].z);
                atomicAdd(o + 3, a[i].w);
            }
        }
    }
}

// ---------------------------------------------------------------------------
// Kernel D: out[n,e] = relu(acc + b_pos + sum_r counts[n,r]*b_dep[r,e]).
// counts row has ~3 nonzeros of 92 -> skip zero types (uniform branch).
// ---------------------------------------------------------------------------
__global__ void __launch_bounds__(256)
final_kernel(const float* __restrict__ acc,
             const float* __restrict__ bpos,
             const float* __restrict__ bdep,
             const float* __restrict__ counts,
             float* __restrict__ out,
             int R) {
    const int n = blockIdx.x;
    const int e = threadIdx.x * 4;

    float4 a  = *(const float4*)(acc  + (size_t)n * D + e);
    const float4 bp = *(const float4*)(bpos + (size_t)n * D + e);
    a.x += bp.x; a.y += bp.y; a.z += bp.z; a.w += bp.w;

    const float* cn = counts + (size_t)n * R;
    for (int r = 0; r < R; ++r) {
        const float cr = cn[r];
        if (cr != 0.0f) {
            const float4 bd = *(const float4*)(bdep + (size_t)r * D + e);
            fma4(a, cr, bd);
        }
    }

    float4 o;
    o.x = fmaxf(a.x, 0.f);
    o.y = fmaxf(a.y, 0.f);
    o.z = fmaxf(a.z, 0.f);
    o.w = fmaxf(a.w, 0.f);
    *(float4*)(out + (size_t)n * D + e) = o;
}

// ---------------------------------------------------------------------------
extern "C" void kernel_launch(void* const* d_in, const int* in_sizes, int n_in,
                              void* d_out, int out_size, void* d_ws, size_t ws_size,
                              hipStream_t stream) {
    const float* x    = (const float*)d_in[0];
    const float* Wpos = (const float*)d_in[1];
    const float* bpos = (const float*)d_in[2];
    const float* Wdep = (const float*)d_in[3];
    const float* bdep = (const float*)d_in[4];
    const int*   etok = (const int*)d_in[5];
    const int*   etyp = (const int*)d_in[6];
    float* out = (float*)d_out;

    const int N = in_sizes[0] / D;   // 150
    const int R = in_sizes[4] / D;   // 92
    const int E = in_sizes[5];       // 450

    // ws layout: [acc N*D f32][counts N*R f32][tcnt R i32][tlist R*E i32]
    float* acc    = (float*)d_ws;
    float* counts = acc + (size_t)N * D;
    int*   tcnt   = (int*)(counts + (size_t)N * R);
    int*   tlist  = tcnt + R;

    const size_t zero_bytes = ((size_t)N * D + (size_t)N * R + (size_t)R) * sizeof(float);
    hipMemsetAsync(d_ws, 0, zero_bytes, stream);

    build_lists<<<(E + 255) / 256, 256, 0, stream>>>(etok, etyp, counts, tcnt, tlist, E, R);
    self_kernel<<<dim3(N, D / DC), 256, 0, stream>>>(x, Wpos, acc);
    dep_kernel<<<dim3(R, D / DC), 256, 0, stream>>>(x, Wdep, tcnt, tlist, acc, E);
    final_kernel<<<N, 256, 0, stream>>>(acc, bpos, bdep, counts, out, R);
}

// Round 4
// 1027.134 us; speedup vs baseline: 1.0627x; 1.0627x over previous
//
#include <hip/hip_runtime.h>
#include <cstdint>
#include <cstddef>

#define D    1024
#define DC   128            // d-chunk per block (reduction-dim slice)
#define NCH  (D / DC)       // 8 chunks
#define TG   16             // max edges processed per pass in dep kernel

__device__ __forceinline__ void fma4(float4& a, float s, const float4& w) {
    a.x = fmaf(s, w.x, a.x);
    a.y = fmaf(s, w.y, a.y);
    a.z = fmaf(s, w.z, a.z);
    a.w = fmaf(s, w.w, a.w);
}

// ---------------------------------------------------------------------------
// Kernel A: per-type edge lists (for dep_kernel) + per-token edge lists
// (for final gather). Only int atomics, 2*E total.
// ---------------------------------------------------------------------------
__global__ void build_lists(const int* __restrict__ etok,
                            const int* __restrict__ etyp,
                            int* __restrict__ tcnt,
                            int* __restrict__ tlist,
                            int* __restrict__ ncnt,
                            int* __restrict__ nlist,
                            int E) {
    int i = blockIdx.x * blockDim.x + threadIdx.x;
    if (i < E) {
        int n = etok[i];
        int r = etyp[i];
        int k  = atomicAdd(&tcnt[r], 1);
        tlist[(size_t)r * E + k] = i;           // store EDGE id
        int k2 = atomicAdd(&ncnt[n], 1);
        nlist[(size_t)n * E + k2] = i;          // store EDGE id
    }
}

// ---------------------------------------------------------------------------
// Kernel B: self term partials. block = (token n, d-chunk c).
// Pself[(c*N + n)*D + e] = sum_{d in chunk} x[n,d] * W_pos[n,d,e]
// Plain float4 stores — no atomics. Streams 512 KB of W_pos per block.
// ---------------------------------------------------------------------------
__global__ void __launch_bounds__(256)
self_kernel(const float* __restrict__ x,
            const float* __restrict__ Wpos,
            float* __restrict__ Pself,
            int N) {
    const int n  = blockIdx.x;
    const int c  = blockIdx.y;
    const int d0 = c * DC;
    const int tid = threadIdx.x;

    __shared__ float xs[DC];
    if (tid < DC) xs[tid] = x[(size_t)n * D + d0 + tid];
    __syncthreads();

    const int e = tid * 4;
    const float* W = Wpos + ((size_t)n * D + d0) * D + e;

    float4 a = {0.f, 0.f, 0.f, 0.f};
    #pragma unroll 4
    for (int dd = 0; dd < DC; dd += 4) {
        const float4 xv = *(const float4*)&xs[dd];
        const float* Wd = W + (size_t)dd * D;
        float4 w0 = *(const float4*)(Wd);
        float4 w1 = *(const float4*)(Wd + D);
        float4 w2 = *(const float4*)(Wd + 2 * D);
        float4 w3 = *(const float4*)(Wd + 3 * D);
        fma4(a, xv.x, w0);
        fma4(a, xv.y, w1);
        fma4(a, xv.z, w2);
        fma4(a, xv.w, w3);
    }

    *(float4*)(Pself + ((size_t)c * N + n) * D + e) = a;
}

// ---------------------------------------------------------------------------
// Kernel C: dep term partials, grouped by type. block = (type r, d-chunk c).
// For each edge i of type r: Pdep[(c*E + i)*D + e] = sum_{d in chunk} x[tok,d]*W_dep[r,d,e]
// Each edge slot written exactly once -> plain stores, no atomics.
// ---------------------------------------------------------------------------
__global__ void __launch_bounds__(256)
dep_kernel(const float* __restrict__ x,
           const float* __restrict__ Wdep,
           const int* __restrict__ etok,
           const int* __restrict__ tcnt,
           const int* __restrict__ tlist,
           float* __restrict__ Pdep,
           int E) {
    const int r  = blockIdx.x;
    const int c  = blockIdx.y;
    const int d0 = c * DC;
    const int cnt = tcnt[r];
    if (cnt == 0) return;

    const int tid = threadIdx.x;
    const int e = tid * 4;

    __shared__ float xs[DC][TG];   // [dd][i], wave-uniform broadcast reads
    __shared__ int   eids[TG];

    const float* W = Wdep + ((size_t)r * D + d0) * D + e;

    for (int base = 0; base < cnt; base += TG) {
        const int m = min(TG, cnt - base);

        __syncthreads();   // previous pass done reading xs/eids
        if (tid < TG) {
            eids[tid] = (tid < m) ? tlist[(size_t)r * E + base + tid] : -1;
        }
        for (int k = tid; k < DC * TG; k += 256) {
            const int dd = k >> 4;       // k / TG
            const int i  = k & (TG - 1); // k % TG
            float v = 0.f;
            if (i < m) {
                const int eid = tlist[(size_t)r * E + base + i];
                const int t   = etok[eid];
                v = x[(size_t)t * D + d0 + dd];
            }
            xs[dd][i] = v;
        }
        __syncthreads();

        float4 a[TG];
        #pragma unroll
        for (int i = 0; i < TG; ++i) a[i] = make_float4(0.f, 0.f, 0.f, 0.f);

        for (int dd = 0; dd < DC; ++dd) {
            const float4 w = *(const float4*)(W + (size_t)dd * D);
            #pragma unroll
            for (int i4 = 0; i4 < TG / 4; ++i4) {
                const float4 xv = *(const float4*)&xs[dd][i4 * 4];
                fma4(a[i4 * 4 + 0], xv.x, w);
                fma4(a[i4 * 4 + 1], xv.y, w);
                fma4(a[i4 * 4 + 2], xv.z, w);
                fma4(a[i4 * 4 + 3], xv.w, w);
            }
        }

        #pragma unroll
        for (int i = 0; i < TG; ++i) {
            if (i < m) {
                *(float4*)(Pdep + ((size_t)c * E + eids[i]) * D + e) = a[i];
            }
        }
    }
}

// ---------------------------------------------------------------------------
// Kernel D: gather + bias + relu.
// out[n,e] = relu( b_pos[n,e] + sum_c Pself[c,n,e]
//                + sum_{edges i of n} ( b_dep[etyp[i],e] + sum_c Pdep[c,i,e] ) )
// ---------------------------------------------------------------------------
__global__ void __launch_bounds__(256)
final_kernel(const float* __restrict__ Pself,
             const float* __restrict__ Pdep,
             const float* __restrict__ bpos,
             const float* __restrict__ bdep,
             const int* __restrict__ etyp,
             const int* __restrict__ ncnt,
             const int* __restrict__ nlist,
             float* __restrict__ out,
             int N, int E) {
    const int n = blockIdx.x;
    const int e = threadIdx.x * 4;

    float4 a = *(const float4*)(bpos + (size_t)n * D + e);

    #pragma unroll
    for (int c = 0; c < NCH; ++c) {
        const float4 p = *(const float4*)(Pself + ((size_t)c * N + n) * D + e);
        a.x += p.x; a.y += p.y; a.z += p.z; a.w += p.w;
    }

    const int deg = ncnt[n];
    for (int k = 0; k < deg; ++k) {
        const int i = nlist[(size_t)n * E + k];
        const int r = etyp[i];
        const float4 bd = *(const float4*)(bdep + (size_t)r * D + e);
        a.x += bd.x; a.y += bd.y; a.z += bd.z; a.w += bd.w;
        #pragma unroll
        for (int c = 0; c < NCH; ++c) {
            const float4 p = *(const float4*)(Pdep + ((size_t)c * E + i) * D + e);
            a.x += p.x; a.y += p.y; a.z += p.z; a.w += p.w;
        }
    }

    float4 o;
    o.x = fmaxf(a.x, 0.f);
    o.y = fmaxf(a.y, 0.f);
    o.z = fmaxf(a.z, 0.f);
    o.w = fmaxf(a.w, 0.f);
    *(float4*)(out + (size_t)n * D + e) = o;
}

// ---------------------------------------------------------------------------
extern "C" void kernel_launch(void* const* d_in, const int* in_sizes, int n_in,
                              void* d_out, int out_size, void* d_ws, size_t ws_size,
                              hipStream_t stream) {
    const float* x    = (const float*)d_in[0];
    const float* Wpos = (const float*)d_in[1];
    const float* bpos = (const float*)d_in[2];
    const float* Wdep = (const float*)d_in[3];
    const float* bdep = (const float*)d_in[4];
    const int*   etok = (const int*)d_in[5];
    const int*   etyp = (const int*)d_in[6];
    float* out = (float*)d_out;

    const int N = in_sizes[0] / D;   // 150
    const int R = in_sizes[4] / D;   // 92
    const int E = in_sizes[5];       // 450

    // ws layout (16B-aligned sections):
    // [Pself NCH*N*D f32][Pdep NCH*E*D f32][tcnt R][ncnt N][tlist R*E][nlist N*E] (ints)
    float* Pself = (float*)d_ws;
    float* Pdep  = Pself + (size_t)NCH * N * D;
    int*   tcnt  = (int*)(Pdep + (size_t)NCH * E * D);
    int*   ncnt  = tcnt + R;
    int*   tlist = ncnt + N;
    int*   nlist = tlist + (size_t)R * E;

    // zero only the two counter arrays (R+N ints)
    hipMemsetAsync(tcnt, 0, (size_t)(R + N) * sizeof(int), stream);

    build_lists<<<(E + 255) / 256, 256, 0, stream>>>(etok, etyp, tcnt, tlist, ncnt, nlist, E);
    self_kernel<<<dim3(N, NCH), 256, 0, stream>>>(x, Wpos, Pself, N);
    dep_kernel<<<dim3(R, NCH), 256, 0, stream>>>(x, Wdep, etok, tcnt, tlist, Pdep, E);
    final_kernel<<<N, 256, 0, stream>>>(Pself, Pdep, bpos, bdep, etyp, ncnt, nlist, out, N, E);
}